// Round 11
// baseline (336.587 us; speedup 1.0000x reference)
//
#include <hip/hip_runtime.h>
#include <stdint.h>

using i32x4  = __attribute__((ext_vector_type(4)))  int;
using i32x16 = __attribute__((ext_vector_type(16))) int;

#define M_TOT 8192
#define N_TOT 4096
#define K_TOT 4096
#define BM 256
#define BN 256
// BK = 64 bytes; 64 K-tiles; LDS ring-3: A 3x16KB @0 | B 3x16KB @48KB = 96KB
// ROLE SPLIT: waves 0-3 (SIMD 0-3) read(k)->MFMA(k); waves 4-7 (SIMD partners)
// MFMA(k) [pre-read at k-1] -> read-ahead(k+1).  Every SIMD keeps one wave in
// the matrix pipe while the partner's ds_reads are served (m114 mechanism).

__device__ __forceinline__ void gload_lds16(const void* g, void* l) {
  __builtin_amdgcn_global_load_lds(
      (const __attribute__((address_space(1))) void*)(uintptr_t)g,
      (__attribute__((address_space(3))) void*)(uint32_t)(uintptr_t)l,
      16, 0, 0);
}

// Repack int32-widened int8 [rows][4096] into swizzled K-chunk tiles:
// chunk (p,kc) = 16KB: [rr 0..255][64B]; physical 16B-slot sp holds logical
// slot sp ^ ((rr>>1)&3).  GEMM staging stays a pure linear copy (rule #21);
// frag ds_read applies the same XOR (8 lanes per 4-bank quad, all quads busy).
__global__ void pack_tiles(const int* __restrict__ a32, const int* __restrict__ b32,
                           int8_t* __restrict__ ap, int8_t* __restrict__ bp,
                           int na, int ntot) {
  int stride = gridDim.x * blockDim.x;
  for (int idx = blockIdx.x * blockDim.x + threadIdx.x; idx < ntot; idx += stride) {
    int i = idx;
    const int* src;
    int8_t* dst;
    if (idx < na) { src = a32; dst = ap; }
    else          { src = b32; dst = bp; i = idx - na; }
    int sp = i & 3;
    int rr = (i >> 2) & 255;
    int kc = (i >> 10) & 63;
    int p  = i >> 16;
    int sl = sp ^ ((rr >> 1) & 3);
    const i32x4* s = (const i32x4*)(src + (((size_t)(p * 256 + rr)) << 12) + kc * 64 + sl * 16);
    i32x4 a = s[0], b = s[1], c = s[2], d = s[3];
    i32x4 o;
    o.x = (a.x & 255) | ((a.y & 255) << 8) | ((a.z & 255) << 16) | (a.w << 24);
    o.y = (b.x & 255) | ((b.y & 255) << 8) | ((b.z & 255) << 16) | (b.w << 24);
    o.z = (c.x & 255) | ((c.y & 255) << 8) | ((c.z & 255) << 16) | (c.w << 24);
    o.w = (d.x & 255) | ((d.y & 255) << 8) | ((d.z & 255) << 16) | (d.w << 24);
    ((i32x4*)dst)[i] = o;
  }
}

// stage one 16KB chunk into ring slot (2 gloads per thread each for A and B)
#define STAGE_AB(KC, SLOT) {                                                \
    const int8_t* _ga = Asrc + (size_t)(KC) * 16384 + stoff;                \
    char* _da = lds + (SLOT) * 16384 + stoff;                               \
    gload_lds16(_ga, _da); gload_lds16(_ga + 8192, _da + 8192);             \
    const int8_t* _gb = Bsrc + (size_t)(KC) * 16384 + stoff;                \
    char* _db = lds + 49152 + (SLOT) * 16384 + stoff;                       \
    gload_lds16(_gb, _db); gload_lds16(_gb + 8192, _db + 8192); }

// load a full tile's frags (12 ds_read_b128) from ring slot
#define LOAD_TILE(FA, FB, SLOT) {                                           \
    const char* _p0 = lds + (SLOT) * 16384;                                 \
    _Pragma("unroll") for (int ks = 0; ks < 2; ++ks) {                      \
      _Pragma("unroll") for (int mi = 0; mi < 4; ++mi)                      \
        FA[ks][mi] = *(const i32x4*)(_p0 + aRow[mi] + kOff[ks]);            \
      _Pragma("unroll") for (int ni = 0; ni < 2; ++ni)                      \
        FB[ks][ni] = *(const i32x4*)(_p0 + 49152 + bRow[ni] + kOff[ks]);    \
    } }

#define MFMA16(FA, FB)                                                      \
    _Pragma("unroll") for (int ks = 0; ks < 2; ++ks)                        \
    _Pragma("unroll") for (int mi = 0; mi < 4; ++mi)                        \
    _Pragma("unroll") for (int ni = 0; ni < 2; ++ni)                        \
      acc[mi][ni] = __builtin_amdgcn_mfma_i32_32x32x32_i8(FA[ks][mi], FB[ks][ni], acc[mi][ni], 0, 0, 0);

// Tile k.  SLOT=k%3, NSLOT=(k+1)%3, SP=k%2 (play set), SR=(k+1)%2.
// Entry vmcnt(0)+barrier: every wave drains its own stage(k+1) parts before
// the barrier => after it, slot (k+1)%3 is complete block-wide (odds read it).
// stage(k+2) overwrites slot (k-1)%3 whose readers finished before entry.
#define INTERVAL(SLOT, NSLOT, SP, SR, KC2, DO_STAGE, DO_AHEAD) {            \
    asm volatile("s_waitcnt vmcnt(0)" ::: "memory");                        \
    __builtin_amdgcn_s_barrier();                                           \
    __builtin_amdgcn_sched_barrier(0);                                      \
    if (DO_STAGE) STAGE_AB(KC2, (KC2) % 3)                                  \
    if (!par) {                                                             \
      LOAD_TILE(fA##SP, fB##SP, SLOT)                                       \
      __builtin_amdgcn_s_setprio(1);                                        \
      MFMA16(fA##SP, fB##SP)                                                \
      __builtin_amdgcn_s_setprio(0);                                        \
    } else {                                                                \
      __builtin_amdgcn_s_setprio(1);                                        \
      MFMA16(fA##SP, fB##SP)                                                \
      __builtin_amdgcn_s_setprio(0);                                        \
      if (DO_AHEAD) LOAD_TILE(fA##SR, fB##SR, NSLOT)                        \
    } }

__global__ __launch_bounds__(512, 2) void gemm_w8a8(
    const int8_t* __restrict__ Apack,  // [32 pm][64 kc][256 r][64B] swizzled
    const int8_t* __restrict__ Bpack,  // [16 pn][64 kc][256 r][64B] swizzled
    const int*    __restrict__ bias,
    const float*  __restrict__ alphap,
    const float*  __restrict__ betap,
    int* __restrict__ out)             // [M][N] int32
{
  __shared__ __align__(16) char lds[98304];  // A ring 3x16KB | B ring 3x16KB

  // XCD-aware 8x8 chunking (FETCH 270->98MB): 32 concurrent wgs/XCD share panels
  const int bid = blockIdx.x;
  const int xcd = bid & 7, wi = bid >> 3;
  const int tm = (xcd & 3) * 8 + (wi & 7);    // 0..31
  const int tn = (xcd >> 2) * 8 + (wi >> 3);  // 0..15

  const int tid = threadIdx.x;
  const int w   = tid >> 6;
  const int l   = tid & 63;
  const int lr  = l & 31;
  const int hi  = l >> 5;
  const int wr  = w & 1;          // wave row 0..1 (w&1 so pair (w, w+4) differs only in role)
  const int wc  = (w >> 1) & 3;   // wave col 0..3
  const int par = w >> 2;         // role: 0 = read->MFMA, 1 = MFMA->read-ahead
  const int stoff = tid * 16;

  const int8_t* Asrc = Apack + ((size_t)tm << 20);  // 64 chunks * 16KB = 1MB
  const int8_t* Bsrc = Bpack + ((size_t)tn << 20);

  const int swz = (lr >> 1) & 3;
  int aRow[4], bRow[2], kOff[2];
#pragma unroll
  for (int mi = 0; mi < 4; ++mi) aRow[mi] = (wr * 128 + mi * 32 + lr) * 64;
#pragma unroll
  for (int ni = 0; ni < 2; ++ni) bRow[ni] = (wc * 64 + ni * 32 + lr) * 64;
#pragma unroll
  for (int ks = 0; ks < 2; ++ks) kOff[ks] = ((((ks << 1) | hi)) ^ swz) * 16;

  i32x16 acc[4][2] = {};
  i32x4 fA0[2][4], fB0[2][2], fA1[2][4], fB1[2][2];  // 2 sets, ping-pong by tile parity

  // prologue: stage tiles 0,1; retire stage 0; odds pre-read tile 0 into set 0
  STAGE_AB(0, 0)
  STAGE_AB(1, 1)
  asm volatile("s_waitcnt vmcnt(4)" ::: "memory");
  __builtin_amdgcn_s_barrier();
  __builtin_amdgcn_sched_barrier(0);
  if (par) LOAD_TILE(fA0, fB0, 0)

  // main: k = 0..59, unroll 6 (ring period 3 x set period 2)
  for (int t = 0; t < 10; ++t) {
    const int kk = t * 6;
    INTERVAL(0, 1, 0, 1, kk + 2, 1, 1)
    INTERVAL(1, 2, 1, 0, kk + 3, 1, 1)
    INTERVAL(2, 0, 0, 1, kk + 4, 1, 1)
    INTERVAL(0, 1, 1, 0, kk + 5, 1, 1)
    INTERVAL(1, 2, 0, 1, kk + 6, 1, 1)
    INTERVAL(2, 0, 1, 0, kk + 7, 1, 1)
  }
  // tail: k=60 (stage 62), 61 (stage 63), 62 (no stage), 63 (no stage/ahead)
  INTERVAL(0, 1, 0, 1, 62, 1, 1)
  INTERVAL(1, 2, 1, 0, 63, 1, 1)
  INTERVAL(2, 0, 0, 1, 0,  0, 1)
  INTERVAL(0, 1, 1, 0, 0,  0, 0)

  // epilogue: y = clip(rint(alpha*acc + beta*bias)) -> int32
  // C/D 32x32 layout: col = lane&31, row = (reg&3) + 8*(reg>>2) + 4*(lane>>5)
  const float alpha = *alphap;
  const float beta  = *betap;
  const int brow = tm * BM, bcol = tn * BN;
#pragma unroll
  for (int ni = 0; ni < 2; ++ni) {
    const int col = bcol + wc * 64 + ni * 32 + lr;
    const float bb = beta * (float)bias[col];
#pragma unroll
    for (int mi = 0; mi < 4; ++mi) {
      const int rbase = brow + wr * 128 + mi * 32 + 4 * hi;
#pragma unroll
      for (int r = 0; r < 16; ++r) {
        const int row = rbase + (r & 3) + 8 * (r >> 2);
        float v = alpha * (float)acc[mi][ni][r] + bb;
        v = rintf(v);
        v = fminf(127.f, fmaxf(-128.f, v));
        out[(size_t)row * N_TOT + col] = (int)v;
      }
    }
  }
}

extern "C" void kernel_launch(void* const* d_in, const int* in_sizes, int n_in,
                              void* d_out, int out_size, void* d_ws, size_t ws_size,
                              hipStream_t stream) {
  const int*   x32    = (const int*)d_in[0];   // (4,2048,4096) int8 widened to int32
  const int*   w32    = (const int*)d_in[1];   // (4096,4096)
  const int*   bias   = (const int*)d_in[2];   // (1,4096)
  const float* alphap = (const float*)d_in[3];
  const float* betap  = (const float*)d_in[4];
  int* out = (int*)d_out;

  int8_t* xp = (int8_t*)d_ws;                  // Apack: 32 MB
  int8_t* wp = xp + (size_t)M_TOT * K_TOT;     // Bpack: 16 MB (48 MB ws total)

  const int na   = (M_TOT * K_TOT) / 16;
  const int ntot = na + (N_TOT * K_TOT) / 16;
  pack_tiles<<<3072, 256, 0, stream>>>(x32, w32, xp, wp, na, ntot);

  gemm_w8a8<<<512, 512, 0, stream>>>(xp, wp, bias, alphap, betap, out);
}

// Round 12
// 206.400 us; speedup vs baseline: 1.6307x; 1.6307x over previous
//
#include <hip/hip_runtime.h>
#include <stdint.h>

using i32x4  = __attribute__((ext_vector_type(4)))  int;
using i32x16 = __attribute__((ext_vector_type(16))) int;

#define M_TOT 8192
#define N_TOT 4096
#define K_TOT 4096
#define BM 256
#define BN 256
// BK = 64 bytes; 64 K-tiles.  A: LDS ring-3 (3x16KB = 48KB).  B: DIRECT TO
// REGISTERS (per-wave frags, frag-ordered pack => 4 coalesced 1KB loads per
// K-tile per wave).  LDS pipe per tile: 64 b128 reads + A-stage ~900cy, now
// BELOW the 1170cy MFMA floor -> matrix pipe becomes the binding resource.

__device__ __forceinline__ void gload_lds16(const void* g, void* l) {
  __builtin_amdgcn_global_load_lds(
      (const __attribute__((address_space(1))) void*)(uintptr_t)g,
      (__attribute__((address_space(3))) void*)(uint32_t)(uintptr_t)l,
      16, 0, 0);
}

// A: swizzled chunks (p,kc)=16KB [rr][64B], slot sp holds sl = sp^((rr>>1)&3).
// B: frag-ordered [pn][kc 64][wc 4][ni 2][ks 2][hi 2][lr 32] x16B so a wave's
//    B frag (ni,ks) is one contiguous 1KB global_load_dwordx4 (lane l -> +l*16).
__global__ void pack_tiles(const int* __restrict__ a32, const int* __restrict__ b32,
                           int8_t* __restrict__ ap, int8_t* __restrict__ bp,
                           int na, int ntot) {
  int stride = gridDim.x * blockDim.x;
  for (int idx = blockIdx.x * blockDim.x + threadIdx.x; idx < ntot; idx += stride) {
    const int* src;
    int8_t* dst;
    size_t selem;
    int i;
    if (idx < na) {            // ---- A decode (unchanged swizzled-chunk) ----
      i = idx; src = a32; dst = ap;
      int sp = i & 3;
      int rr = (i >> 2) & 255;
      int kc = (i >> 10) & 63;
      int p  = i >> 16;
      int sl = sp ^ ((rr >> 1) & 3);
      selem = (((size_t)(p * 256 + rr)) << 12) + kc * 64 + sl * 16;
    } else {                   // ---- B decode (frag-ordered for reg load) ----
      i = idx - na; src = b32; dst = bp;
      int lr = i & 31;
      int hi = (i >> 5) & 1;
      int ks = (i >> 6) & 1;
      int ni = (i >> 7) & 1;
      int wc = (i >> 8) & 3;
      int kc = (i >> 10) & 63;
      int pn = i >> 16;
      int row = pn * 256 + wc * 64 + ni * 32 + lr;
      int kb  = kc * 64 + ks * 32 + hi * 16;
      selem = (size_t)row * 4096 + kb;
    }
    const i32x4* s = (const i32x4*)(src + selem);
    i32x4 a = s[0], b = s[1], c = s[2], d = s[3];
    i32x4 o;
    o.x = (a.x & 255) | ((a.y & 255) << 8) | ((a.z & 255) << 16) | (a.w << 24);
    o.y = (b.x & 255) | ((b.y & 255) << 8) | ((b.z & 255) << 16) | (b.w << 24);
    o.z = (c.x & 255) | ((c.y & 255) << 8) | ((c.z & 255) << 16) | (c.w << 24);
    o.w = (d.x & 255) | ((d.y & 255) << 8) | ((d.z & 255) << 16) | (d.w << 24);
    ((i32x4*)dst)[i] = o;
  }
}

// stage one 16KB A chunk into ring slot (2 gloads per thread)
#define STAGE_A(KC, SLOT) {                                                 \
    const int8_t* _g = Asrc + (size_t)(KC) * 16384 + stoff;                 \
    char* _d = lds + (SLOT) * 16384 + stoff;                                \
    gload_lds16(_g, _d); gload_lds16(_g + 8192, _d + 8192); }

// 4 coalesced 1KB loads: B frags (ni,ks) for K-tile KC into register set SET
#define BLOAD(KC, SET) {                                                    \
    const int8_t* _b = Bw + (size_t)(KC) * 16384;                           \
    Bs##SET[0][0] = *(const i32x4*)(_b);                                    \
    Bs##SET[0][1] = *(const i32x4*)(_b + 1024);                             \
    Bs##SET[1][0] = *(const i32x4*)(_b + 2048);                             \
    Bs##SET[1][1] = *(const i32x4*)(_b + 3072); }

// Tile k: SLOT = k%3 (A slot + B reg set), NS = (k+2)%3 (stage/load target).
// Entry vmcnt(6) retires the GROUP issued at body k-2 (groups are fenced by
// sched_barrier(0), so the count is robust to intra-group reordering):
// A slot k%3 valid + B set k%3 registers retired.  Barrier publishes A.
#define INTERVAL(SLOT, NS, VM, KC2, DO) {                                   \
    asm volatile("s_waitcnt vmcnt(" VM ")" ::: "memory");                   \
    __builtin_amdgcn_s_barrier();                                           \
    __builtin_amdgcn_sched_barrier(0);                                      \
    if (DO) { STAGE_A(KC2, NS) BLOAD(KC2, NS) }                             \
    { const char* _pa = lds + (SLOT) * 16384;                               \
      _Pragma("unroll") for (int ks = 0; ks < 2; ++ks)                      \
      _Pragma("unroll") for (int mi = 0; mi < 4; ++mi)                      \
        Af[ks][mi] = *(const i32x4*)(_pa + aRow[mi] + kOff[ks]); }          \
    __builtin_amdgcn_s_setprio(1);                                          \
    _Pragma("unroll") for (int ks = 0; ks < 2; ++ks)                        \
    _Pragma("unroll") for (int mi = 0; mi < 4; ++mi)                        \
    _Pragma("unroll") for (int ni = 0; ni < 2; ++ni)                        \
      acc[mi][ni] = __builtin_amdgcn_mfma_i32_32x32x32_i8(Af[ks][mi], Bs##SLOT[ni][ks], acc[mi][ni], 0, 0, 0); \
    __builtin_amdgcn_s_setprio(0); }

__global__ __launch_bounds__(512, 2) void gemm_w8a8(
    const int8_t* __restrict__ Apack,  // [32 pm][64 kc][256 r][64B] swizzled
    const int8_t* __restrict__ Bpack,  // [16 pn][64 kc][4 wc][2 ni][2 ks][64 l][16B]
    const int*    __restrict__ bias,
    const float*  __restrict__ alphap,
    const float*  __restrict__ betap,
    int* __restrict__ out)             // [M][N] int32
{
  __shared__ __align__(16) char lds[49152];  // A ring 3x16KB (B never touches LDS)

  // XCD-aware 8x8 chunking (FETCH 270->98MB): 32 concurrent wgs/XCD share panels
  const int bid = blockIdx.x;
  const int xcd = bid & 7, wi = bid >> 3;
  const int tm = (xcd & 3) * 8 + (wi & 7);    // 0..31
  const int tn = (xcd >> 2) * 8 + (wi >> 3);  // 0..15

  const int tid = threadIdx.x;
  const int w   = tid >> 6;
  const int l   = tid & 63;
  const int lr  = l & 31;
  const int hi  = l >> 5;
  const int wr  = w >> 2;   // 0..1
  const int wc  = w & 3;    // 0..3
  const int stoff = tid * 16;

  const int8_t* Asrc = Apack + ((size_t)tm << 20);               // 64 x 16KB
  const int8_t* Bw   = Bpack + ((size_t)tn << 20) + wc * 4096 + l * 16;

  const int swz = (lr >> 1) & 3;
  int aRow[4], kOff[2];
#pragma unroll
  for (int mi = 0; mi < 4; ++mi) aRow[mi] = (wr * 128 + mi * 32 + lr) * 64;
#pragma unroll
  for (int ks = 0; ks < 2; ++ks) kOff[ks] = ((((ks << 1) | hi)) ^ swz) * 16;

  i32x16 acc[4][2] = {};
  i32x4 Af[2][4];
  i32x4 Bs0[2][2], Bs1[2][2], Bs2[2][2];   // B reg sets, period 3

  // prologue: groups {sA0,B0} and {sA1,B1}, fenced so group order is strict
  STAGE_A(0, 0) BLOAD(0, 0)
  __builtin_amdgcn_sched_barrier(0);
  STAGE_A(1, 1) BLOAD(1, 1)
  __builtin_amdgcn_sched_barrier(0);

  // k = 0 entry: vmcnt(6) retires group {sA0,B0}
  INTERVAL(0, 2, "6", 2, 1)
  // k = 1..60
  for (int t = 0; t < 20; ++t) {
    const int kk = t * 3;
    INTERVAL(1, 0, "6", kk + 3, 1)
    INTERVAL(2, 1, "6", kk + 4, 1)
    INTERVAL(0, 2, "6", kk + 5, 1)
  }
  // k = 61 (stage/load 63), 62 (none), 63 (drain)
  INTERVAL(1, 0, "6", 63, 1)
  INTERVAL(2, 1, "6", 0, 0)
  INTERVAL(0, 2, "0", 0, 0)

  // epilogue: y = clip(rint(alpha*acc + beta*bias)) -> int32
  // C/D 32x32 layout: col = lane&31, row = (reg&3) + 8*(reg>>2) + 4*(lane>>5)
  const float alpha = *alphap;
  const float beta  = *betap;
  const int brow = tm * BM, bcol = tn * BN;
#pragma unroll
  for (int ni = 0; ni < 2; ++ni) {
    const int col = bcol + wc * 64 + ni * 32 + lr;
    const float bb = beta * (float)bias[col];
#pragma unroll
    for (int mi = 0; mi < 4; ++mi) {
      const int rbase = brow + wr * 128 + mi * 32 + 4 * hi;
#pragma unroll
      for (int r = 0; r < 16; ++r) {
        const int row = rbase + (r & 3) + 8 * (r >> 2);
        float v = alpha * (float)acc[mi][ni][r] + bb;
        v = rintf(v);
        v = fminf(127.f, fmaxf(-128.f, v));
        out[(size_t)row * N_TOT + col] = (int)v;
      }
    }
  }
}

extern "C" void kernel_launch(void* const* d_in, const int* in_sizes, int n_in,
                              void* d_out, int out_size, void* d_ws, size_t ws_size,
                              hipStream_t stream) {
  const int*   x32    = (const int*)d_in[0];   // (4,2048,4096) int8 widened to int32
  const int*   w32    = (const int*)d_in[1];   // (4096,4096)
  const int*   bias   = (const int*)d_in[2];   // (1,4096)
  const float* alphap = (const float*)d_in[3];
  const float* betap  = (const float*)d_in[4];
  int* out = (int*)d_out;

  int8_t* xp = (int8_t*)d_ws;                  // Apack: 32 MB
  int8_t* wp = xp + (size_t)M_TOT * K_TOT;     // Bpack: 16 MB (48 MB ws total)

  const int na   = (M_TOT * K_TOT) / 16;
  const int ntot = na + (N_TOT * K_TOT) / 16;
  pack_tiles<<<3072, 256, 0, stream>>>(x32, w32, xp, wp, na, ntot);

  gemm_w8a8<<<512, 512, 0, stream>>>(xp, wp, bias, alphap, betap, out);
}

// Round 13
// 202.425 us; speedup vs baseline: 1.6628x; 1.0196x over previous
//
#include <hip/hip_runtime.h>
#include <stdint.h>

using i32x4  = __attribute__((ext_vector_type(4)))  int;
using i32x16 = __attribute__((ext_vector_type(16))) int;

#define M_TOT 8192
#define N_TOT 4096
#define K_TOT 4096
#define BM 256
#define BN 256
// 4 waves (2x2), wave tile 128x128 (acc[4][4], reads/MFMA = 0.5 — halved),
// BK = 128B per barrier interval (32 intervals), LDS ring-2 128KB.
// 1 wave/SIMD: the wave owns its SIMD issue stream -> SGB interleave has
// full control; triple-rotated frag sets keep ds_read WAR-free.

__device__ __forceinline__ void gload_lds16(const void* g, void* l) {
  __builtin_amdgcn_global_load_lds(
      (const __attribute__((address_space(1))) void*)(uintptr_t)g,
      (__attribute__((address_space(3))) void*)(uint32_t)(uintptr_t)l,
      16, 0, 0);
}

// Repack int32-widened int8 [rows][4096] into swizzled K-chunk tiles:
// chunk (p,kc) = 16KB: [rr 0..255][64B]; physical 16B-slot sp holds logical
// slot sp ^ ((rr>>1)&3).  GEMM staging stays a pure linear copy (rule #21);
// frag ds_read applies the same XOR (8 lanes per 4-bank quad, all quads busy).
__global__ void pack_tiles(const int* __restrict__ a32, const int* __restrict__ b32,
                           int8_t* __restrict__ ap, int8_t* __restrict__ bp,
                           int na, int ntot) {
  int stride = gridDim.x * blockDim.x;
  for (int idx = blockIdx.x * blockDim.x + threadIdx.x; idx < ntot; idx += stride) {
    int i = idx;
    const int* src;
    int8_t* dst;
    if (idx < na) { src = a32; dst = ap; }
    else          { src = b32; dst = bp; i = idx - na; }
    int sp = i & 3;
    int rr = (i >> 2) & 255;
    int kc = (i >> 10) & 63;
    int p  = i >> 16;
    int sl = sp ^ ((rr >> 1) & 3);
    const i32x4* s = (const i32x4*)(src + (((size_t)(p * 256 + rr)) << 12) + kc * 64 + sl * 16);
    i32x4 a = s[0], b = s[1], c = s[2], d = s[3];
    i32x4 o;
    o.x = (a.x & 255) | ((a.y & 255) << 8) | ((a.z & 255) << 16) | (a.w << 24);
    o.y = (b.x & 255) | ((b.y & 255) << 8) | ((b.z & 255) << 16) | (b.w << 24);
    o.z = (c.x & 255) | ((c.y & 255) << 8) | ((c.z & 255) << 16) | (c.w << 24);
    o.w = (d.x & 255) | ((d.y & 255) << 8) | ((d.z & 255) << 16) | (d.w << 24);
    ((i32x4*)dst)[i] = o;
  }
}

// stage interval I (chunks 2I, 2I+1 = 32KB A + 32KB B) into LDS slot S.
// 256 threads x 16B cover 4KB per round; 8 rounds per tensor.
#define STAGE2(I, S) {                                                      \
    const int8_t* _ga = Asrc + ((size_t)(I) << 15) + stoff;                 \
    char* _da = lds + (S) * 32768 + stoff;                                  \
    gload_lds16(_ga,          _da);          gload_lds16(_ga + 4096,  _da + 4096);  \
    gload_lds16(_ga + 8192,   _da + 8192);   gload_lds16(_ga + 12288, _da + 12288); \
    gload_lds16(_ga + 16384,  _da + 16384);  gload_lds16(_ga + 20480, _da + 20480); \
    gload_lds16(_ga + 24576,  _da + 24576);  gload_lds16(_ga + 28672, _da + 28672); \
    const int8_t* _gb = Bsrc + ((size_t)(I) << 15) + stoff;                 \
    char* _db = lds + 65536 + (S) * 32768 + stoff;                          \
    gload_lds16(_gb,          _db);          gload_lds16(_gb + 4096,  _db + 4096);  \
    gload_lds16(_gb + 8192,   _db + 8192);   gload_lds16(_gb + 12288, _db + 12288); \
    gload_lds16(_gb + 16384,  _db + 16384);  gload_lds16(_gb + 20480, _db + 20480); \
    gload_lds16(_gb + 24576,  _db + 24576);  gload_lds16(_gb + 28672, _db + 28672); }

// load frag set SET (4 A + 4 B ds_read_b128) for K-step KS (0..3) from slot S
#define LOAD_SET(SET, S, KS) {                                              \
    const char* _pa = lds + (S) * 32768 + kOff[KS];                         \
    const char* _pb = _pa + 65536;                                          \
    Af##SET[0] = *(const i32x4*)(_pa + aRow[0]);                            \
    Af##SET[1] = *(const i32x4*)(_pa + aRow[1]);                            \
    Af##SET[2] = *(const i32x4*)(_pa + aRow[2]);                            \
    Af##SET[3] = *(const i32x4*)(_pa + aRow[3]);                            \
    Bf##SET[0] = *(const i32x4*)(_pb + bRow[0]);                            \
    Bf##SET[1] = *(const i32x4*)(_pb + bRow[1]);                            \
    Bf##SET[2] = *(const i32x4*)(_pb + bRow[2]);                            \
    Bf##SET[3] = *(const i32x4*)(_pb + bRow[3]); }

// 16 MFMAs: every A frag feeds 4 MFMAs (reads/MFMA = 0.5)
#define MFMA16(SET)                                                         \
    _Pragma("unroll") for (int mi = 0; mi < 4; ++mi)                        \
    _Pragma("unroll") for (int ni = 0; ni < 4; ++ni)                        \
      acc[mi][ni] = __builtin_amdgcn_mfma_i32_32x32x32_i8(Af##SET[mi], Bf##SET[ni], acc[mi][ni], 0, 0, 0);

#define SGB(m, n) __builtin_amdgcn_sched_group_barrier((m), (n), 0)
#define PAIR SGB(0x100, 1); SGB(0x8, 2);
#define PAIR8 PAIR PAIR PAIR PAIR PAIR PAIR PAIR PAIR

// Interval I on slot S: entry vmcnt(0) retires stage(I) (issued a full
// interval ~4400cy ago); barrier publishes; stage(I+1) into S^1; 4 K-step
// phases with set rotation 0,1,2,0 (WAR distance >= 2 phases).
// SGB: 16 VMEM first, 8 DS (ks0), then 3x{1 DS,2 MFMA}x8, then 16 MFMA.
#define INTERVAL(I, S, DO_STAGE) {                                          \
    asm volatile("s_waitcnt vmcnt(0)" ::: "memory");                        \
    __builtin_amdgcn_s_barrier();                                           \
    __builtin_amdgcn_sched_barrier(0);                                      \
    if (DO_STAGE) STAGE2((I) + 1, (S) ^ 1)                                  \
    LOAD_SET(0, S, 0)                                                       \
    LOAD_SET(1, S, 1)                                                       \
    __builtin_amdgcn_s_setprio(1);                                          \
    MFMA16(0)                                                               \
    LOAD_SET(2, S, 2)                                                       \
    MFMA16(1)                                                               \
    LOAD_SET(0, S, 3)                                                       \
    MFMA16(2)                                                               \
    MFMA16(0)                                                               \
    __builtin_amdgcn_s_setprio(0);                                          \
    SGB(0x10, 16);                                                          \
    SGB(0x100, 8);                                                          \
    PAIR8 PAIR8 PAIR8                                                       \
    SGB(0x8, 16); }

__global__ __launch_bounds__(256, 1) void gemm_w8a8(
    const int8_t* __restrict__ Apack,  // [32 pm][64 kc][256 r][64B] swizzled
    const int8_t* __restrict__ Bpack,  // [16 pn][64 kc][256 r][64B] swizzled
    const int*    __restrict__ bias,
    const float*  __restrict__ alphap,
    const float*  __restrict__ betap,
    int* __restrict__ out)             // [M][N] int32
{
  __shared__ __align__(16) char lds[131072];  // A 2x32KB @0 | B 2x32KB @64KB

  // XCD-aware 8x8 chunking (FETCH 270->98MB): 32 concurrent wgs/XCD share panels
  const int bid = blockIdx.x;
  const int xcd = bid & 7, wi = bid >> 3;
  const int tm = (xcd & 3) * 8 + (wi & 7);    // 0..31
  const int tn = (xcd >> 2) * 8 + (wi >> 3);  // 0..15

  const int tid = threadIdx.x;     // 256 threads, 4 waves
  const int w   = tid >> 6;
  const int l   = tid & 63;
  const int lr  = l & 31;
  const int hi  = l >> 5;
  const int wr  = w >> 1;   // 0..1
  const int wc  = w & 1;    // 0..1
  const int stoff = tid * 16;

  const int8_t* Asrc = Apack + ((size_t)tm << 20);  // 64 x 16KB = 1MB
  const int8_t* Bsrc = Bpack + ((size_t)tn << 20);

  const int swz = (lr >> 1) & 3;
  int aRow[4], bRow[4], kOff[4];
#pragma unroll
  for (int mi = 0; mi < 4; ++mi) aRow[mi] = (wr * 128 + mi * 32 + lr) * 64;
#pragma unroll
  for (int ni = 0; ni < 4; ++ni) bRow[ni] = (wc * 128 + ni * 32 + lr) * 64;
#pragma unroll
  for (int ks = 0; ks < 4; ++ks)
    kOff[ks] = (ks >> 1) * 16384 + (((((ks & 1) << 1) | hi)) ^ swz) * 16;

  i32x16 acc[4][4] = {};
  i32x4 Af0[4], Bf0[4], Af1[4], Bf1[4], Af2[4], Bf2[4];  // 3 rotating sets

  // prologue: stage interval 0 into slot 0
  STAGE2(0, 0)

  // 32 intervals, ring-2 (slot = I&1), stage I+1 during I
  for (int t = 0; t < 15; ++t) {
    const int I = t * 2;
    INTERVAL(I + 0, 0, 1)
    INTERVAL(I + 1, 1, 1)
  }
  INTERVAL(30, 0, 1)
  INTERVAL(31, 1, 0)

  // epilogue: y = clip(rint(alpha*acc + beta*bias)) -> int32
  // C/D 32x32 layout: col = lane&31, row = (reg&3) + 8*(reg>>2) + 4*(lane>>5)
  const float alpha = *alphap;
  const float beta  = *betap;
  const int brow = tm * BM, bcol = tn * BN;
#pragma unroll
  for (int ni = 0; ni < 4; ++ni) {
    const int col = bcol + wc * 128 + ni * 32 + lr;
    const float bb = beta * (float)bias[col];
#pragma unroll
    for (int mi = 0; mi < 4; ++mi) {
      const int rbase = brow + wr * 128 + mi * 32 + 4 * hi;
#pragma unroll
      for (int r = 0; r < 16; ++r) {
        const int row = rbase + (r & 3) + 8 * (r >> 2);
        float v = alpha * (float)acc[mi][ni][r] + bb;
        v = rintf(v);
        v = fminf(127.f, fmaxf(-128.f, v));
        out[(size_t)row * N_TOT + col] = (int)v;
      }
    }
  }
}

extern "C" void kernel_launch(void* const* d_in, const int* in_sizes, int n_in,
                              void* d_out, int out_size, void* d_ws, size_t ws_size,
                              hipStream_t stream) {
  const int*   x32    = (const int*)d_in[0];   // (4,2048,4096) int8 widened to int32
  const int*   w32    = (const int*)d_in[1];   // (4096,4096)
  const int*   bias   = (const int*)d_in[2];   // (1,4096)
  const float* alphap = (const float*)d_in[3];
  const float* betap  = (const float*)d_in[4];
  int* out = (int*)d_out;

  int8_t* xp = (int8_t*)d_ws;                  // Apack: 32 MB
  int8_t* wp = xp + (size_t)M_TOT * K_TOT;     // Bpack: 16 MB (48 MB ws total)

  const int na   = (M_TOT * K_TOT) / 16;
  const int ntot = na + (N_TOT * K_TOT) / 16;
  pack_tiles<<<3072, 256, 0, stream>>>(x32, w32, xp, wp, na, ntot);

  gemm_w8a8<<<512, 256, 0, stream>>>(xp, wp, bias, alphap, betap, out);
}

// Round 14
// 200.506 us; speedup vs baseline: 1.6787x; 1.0096x over previous
//
#include <hip/hip_runtime.h>
#include <stdint.h>

using i32x4  = __attribute__((ext_vector_type(4)))  int;
using i32x16 = __attribute__((ext_vector_type(16))) int;

#define M_TOT 8192
#define N_TOT 4096
#define K_TOT 4096
#define BM 256
#define BN 256
// 4 waves (2x2), wave tile 128x128: reads/MFMA = 0.5 -> per-CU LDS-read term
// 20.5us << MFMA 62.4us.  BK=128B interval, ring-2 LDS 128KB, 1 block/CU.
// R13 fix: NO SGB pacing (it stretched reads to MFMA retire rate), 4 WAR-free
// frag sets, all 32 ds_reads front-loaded -> compiler's counted lgkmcnt lets
// set-k MFMAs run while sets k+1..3 are still being served.

__device__ __forceinline__ void gload_lds16(const void* g, void* l) {
  __builtin_amdgcn_global_load_lds(
      (const __attribute__((address_space(1))) void*)(uintptr_t)g,
      (__attribute__((address_space(3))) void*)(uint32_t)(uintptr_t)l,
      16, 0, 0);
}

// Repack int32-widened int8 [rows][4096] into swizzled K-chunk tiles:
// chunk (p,kc) = 16KB: [rr 0..255][64B]; physical 16B-slot sp holds logical
// slot sp ^ ((rr>>1)&3).  GEMM staging stays a pure linear copy (rule #21);
// frag ds_read applies the same XOR (8 lanes per 4-bank quad, all quads busy).
__global__ void pack_tiles(const int* __restrict__ a32, const int* __restrict__ b32,
                           int8_t* __restrict__ ap, int8_t* __restrict__ bp,
                           int na, int ntot) {
  int stride = gridDim.x * blockDim.x;
  for (int idx = blockIdx.x * blockDim.x + threadIdx.x; idx < ntot; idx += stride) {
    int i = idx;
    const int* src;
    int8_t* dst;
    if (idx < na) { src = a32; dst = ap; }
    else          { src = b32; dst = bp; i = idx - na; }
    int sp = i & 3;
    int rr = (i >> 2) & 255;
    int kc = (i >> 10) & 63;
    int p  = i >> 16;
    int sl = sp ^ ((rr >> 1) & 3);
    const i32x4* s = (const i32x4*)(src + (((size_t)(p * 256 + rr)) << 12) + kc * 64 + sl * 16);
    i32x4 a = s[0], b = s[1], c = s[2], d = s[3];
    i32x4 o;
    o.x = (a.x & 255) | ((a.y & 255) << 8) | ((a.z & 255) << 16) | (a.w << 24);
    o.y = (b.x & 255) | ((b.y & 255) << 8) | ((b.z & 255) << 16) | (b.w << 24);
    o.z = (c.x & 255) | ((c.y & 255) << 8) | ((c.z & 255) << 16) | (c.w << 24);
    o.w = (d.x & 255) | ((d.y & 255) << 8) | ((d.z & 255) << 16) | (d.w << 24);
    ((i32x4*)dst)[i] = o;
  }
}

// stage interval I (chunks 2I, 2I+1 = 32KB A + 32KB B) into LDS slot S.
// 256 threads x 16B = 4KB per gload round; 8 rounds per tensor.
#define STAGE2(I, S) {                                                      \
    const int8_t* _ga = Asrc + ((size_t)(I) << 15) + stoff;                 \
    char* _da = lds + (S) * 32768 + stoff;                                  \
    gload_lds16(_ga,          _da);          gload_lds16(_ga + 4096,  _da + 4096);  \
    gload_lds16(_ga + 8192,   _da + 8192);   gload_lds16(_ga + 12288, _da + 12288); \
    gload_lds16(_ga + 16384,  _da + 16384);  gload_lds16(_ga + 20480, _da + 20480); \
    gload_lds16(_ga + 24576,  _da + 24576);  gload_lds16(_ga + 28672, _da + 28672); \
    const int8_t* _gb = Bsrc + ((size_t)(I) << 15) + stoff;                 \
    char* _db = lds + 65536 + (S) * 32768 + stoff;                          \
    gload_lds16(_gb,          _db);          gload_lds16(_gb + 4096,  _db + 4096);  \
    gload_lds16(_gb + 8192,   _db + 8192);   gload_lds16(_gb + 12288, _db + 12288); \
    gload_lds16(_gb + 16384,  _db + 16384);  gload_lds16(_gb + 20480, _db + 20480); \
    gload_lds16(_gb + 24576,  _db + 24576);  gload_lds16(_gb + 28672, _db + 28672); }

// load frag set SET (4 A + 4 B ds_read_b128) for K-step KS (0..3) from slot S
#define LOAD_SET(SET, S, KS) {                                              \
    const char* _pa = lds + (S) * 32768 + kOff[KS];                         \
    const char* _pb = _pa + 65536;                                          \
    Af##SET[0] = *(const i32x4*)(_pa + aRow[0]);                            \
    Af##SET[1] = *(const i32x4*)(_pa + aRow[1]);                            \
    Af##SET[2] = *(const i32x4*)(_pa + aRow[2]);                            \
    Af##SET[3] = *(const i32x4*)(_pa + aRow[3]);                            \
    Bf##SET[0] = *(const i32x4*)(_pb + bRow[0]);                            \
    Bf##SET[1] = *(const i32x4*)(_pb + bRow[1]);                            \
    Bf##SET[2] = *(const i32x4*)(_pb + bRow[2]);                            \
    Bf##SET[3] = *(const i32x4*)(_pb + bRow[3]); }

// 16 independent MFMAs (one per acc register)
#define MFMA16(SET)                                                         \
    _Pragma("unroll") for (int mi = 0; mi < 4; ++mi)                        \
    _Pragma("unroll") for (int ni = 0; ni < 4; ++ni)                        \
      acc[mi][ni] = __builtin_amdgcn_mfma_i32_32x32x32_i8(Af##SET[mi], Bf##SET[ni], acc[mi][ni], 0, 0, 0);

// Interval I on slot S: entry vmcnt(0) retires stage(I) (issued a full
// interval ago); barrier publishes; stage(I+1) into S^1; ALL 32 ds_reads
// front-loaded into 4 WAR-free sets; then 64 MFMAs.  Compiler inserts
// counted lgkmcnt before each MFMA16 so matrix work starts at ~set0-landing.
#define INTERVAL(I, S, DO_STAGE) {                                          \
    asm volatile("s_waitcnt vmcnt(0)" ::: "memory");                        \
    __builtin_amdgcn_s_barrier();                                           \
    __builtin_amdgcn_sched_barrier(0);                                      \
    if (DO_STAGE) STAGE2((I) + 1, (S) ^ 1)                                  \
    LOAD_SET(0, S, 0)                                                       \
    LOAD_SET(1, S, 1)                                                       \
    LOAD_SET(2, S, 2)                                                       \
    LOAD_SET(3, S, 3)                                                       \
    MFMA16(0)                                                               \
    MFMA16(1)                                                               \
    MFMA16(2)                                                               \
    MFMA16(3)                                                               \
  }

__global__ __launch_bounds__(256, 1) void gemm_w8a8(
    const int8_t* __restrict__ Apack,  // [32 pm][64 kc][256 r][64B] swizzled
    const int8_t* __restrict__ Bpack,  // [16 pn][64 kc][256 r][64B] swizzled
    const int*    __restrict__ bias,
    const float*  __restrict__ alphap,
    const float*  __restrict__ betap,
    int* __restrict__ out)             // [M][N] int32
{
  __shared__ __align__(16) char lds[131072];  // A 2x32KB @0 | B 2x32KB @64KB

  // XCD-aware 8x8 chunking (FETCH 270->98MB): 32 concurrent wgs/XCD share panels
  const int bid = blockIdx.x;
  const int xcd = bid & 7, wi = bid >> 3;
  const int tm = (xcd & 3) * 8 + (wi & 7);    // 0..31
  const int tn = (xcd >> 2) * 8 + (wi >> 3);  // 0..15

  const int tid = threadIdx.x;     // 256 threads, 4 waves
  const int w   = tid >> 6;
  const int l   = tid & 63;
  const int lr  = l & 31;
  const int hi  = l >> 5;
  const int wr  = w >> 1;   // 0..1
  const int wc  = w & 1;    // 0..1
  const int stoff = tid * 16;

  const int8_t* Asrc = Apack + ((size_t)tm << 20);  // 64 x 16KB = 1MB
  const int8_t* Bsrc = Bpack + ((size_t)tn << 20);

  const int swz = (lr >> 1) & 3;
  int aRow[4], bRow[4], kOff[4];
#pragma unroll
  for (int mi = 0; mi < 4; ++mi) aRow[mi] = (wr * 128 + mi * 32 + lr) * 64;
#pragma unroll
  for (int ni = 0; ni < 4; ++ni) bRow[ni] = (wc * 128 + ni * 32 + lr) * 64;
#pragma unroll
  for (int ks = 0; ks < 4; ++ks)
    kOff[ks] = (ks >> 1) * 16384 + (((((ks & 1) << 1) | hi)) ^ swz) * 16;

  i32x16 acc[4][4] = {};
  i32x4 Af0[4], Bf0[4], Af1[4], Bf1[4], Af2[4], Bf2[4], Af3[4], Bf3[4];

  // prologue: stage interval 0 into slot 0
  STAGE2(0, 0)

  // 32 intervals, ring-2 (slot = I&1), stage I+1 during I
  for (int t = 0; t < 15; ++t) {
    const int I = t * 2;
    INTERVAL(I + 0, 0, 1)
    INTERVAL(I + 1, 1, 1)
  }
  INTERVAL(30, 0, 1)
  INTERVAL(31, 1, 0)

  // epilogue: y = clip(rint(alpha*acc + beta*bias)) -> int32
  // C/D 32x32 layout: col = lane&31, row = (reg&3) + 8*(reg>>2) + 4*(lane>>5)
  const float alpha = *alphap;
  const float beta  = *betap;
  const int brow = tm * BM, bcol = tn * BN;
#pragma unroll
  for (int ni = 0; ni < 4; ++ni) {
    const int col = bcol + wc * 128 + ni * 32 + lr;
    const float bb = beta * (float)bias[col];
#pragma unroll
    for (int mi = 0; mi < 4; ++mi) {
      const int rbase = brow + wr * 128 + mi * 32 + 4 * hi;
#pragma unroll
      for (int r = 0; r < 16; ++r) {
        const int row = rbase + (r & 3) + 8 * (r >> 2);
        float v = alpha * (float)acc[mi][ni][r] + bb;
        v = rintf(v);
        v = fminf(127.f, fmaxf(-128.f, v));
        out[(size_t)row * N_TOT + col] = (int)v;
      }
    }
  }
}

extern "C" void kernel_launch(void* const* d_in, const int* in_sizes, int n_in,
                              void* d_out, int out_size, void* d_ws, size_t ws_size,
                              hipStream_t stream) {
  const int*   x32    = (const int*)d_in[0];   // (4,2048,4096) int8 widened to int32
  const int*   w32    = (const int*)d_in[1];   // (4096,4096)
  const int*   bias   = (const int*)d_in[2];   // (1,4096)
  const float* alphap = (const float*)d_in[3];
  const float* betap  = (const float*)d_in[4];
  int* out = (int*)d_out;

  int8_t* xp = (int8_t*)d_ws;                  // Apack: 32 MB
  int8_t* wp = xp + (size_t)M_TOT * K_TOT;     // Bpack: 16 MB (48 MB ws total)

  const int na   = (M_TOT * K_TOT) / 16;
  const int ntot = na + (N_TOT * K_TOT) / 16;
  pack_tiles<<<3072, 256, 0, stream>>>(x32, w32, xp, wp, na, ntot);

  gemm_w8a8<<<512, 256, 0, stream>>>(xp, wp, bias, alphap, betap, out);
}